// Round 16
// baseline (444.486 us; speedup 1.0000x reference)
//
#include <hip/hip_runtime.h>
#include <hip/hip_bf16.h>

#define BT 65536
#define DD 512
#define HH 512
#define NE 32
#define CAP 5120
#define BM 64
#define NRB 80   /* CAP/BM */

typedef float  f32x4  __attribute__((ext_vector_type(4)));
typedef short  bf16x8 __attribute__((ext_vector_type(8)));

__device__ __forceinline__ unsigned short f2bf(float f){
    unsigned int u = __builtin_bit_cast(unsigned int, f);
    unsigned int r = (u + 0x7fffu + ((u >> 16) & 1u)) >> 16;
    return (unsigned short)r;
}
__device__ __forceinline__ float bf2f(unsigned short h){
    unsigned int u = ((unsigned int)h) << 16;
    return __builtin_bit_cast(float, u);
}

// ---------------- Wg -> hi/lo MFMA A-fragments ----------------
__global__ __launch_bounds__(256) void k_wgprep(
    const float* __restrict__ Wg,
    unsigned short* __restrict__ WgHf, unsigned short* __restrict__ WgLf)
{
    int entry = blockIdx.x * 256 + threadIdx.x;   // 8 blocks x 256 = 2048 entries
    int ln = entry & 63;
    unsigned short h[8], l[8];
    #pragma unroll
    for (int j = 0; j < 8; j++){
        int d = ((entry >> 6) & 15)*32 + (ln >> 4)*8 + j;
        int e = (entry >> 10)*16 + (ln & 15);
        float v = Wg[d*NE + e];
        unsigned short hi = f2bf(v);
        h[j] = hi;
        l[j] = f2bf(v - bf2f(hi));
    }
    *(bf16x8*)(WgHf + (size_t)entry*8) = *(bf16x8*)h;
    *(bf16x8*)(WgLf + (size_t)entry*8) = *(bf16x8*)l;
}

// ---------------- conv: blocks [0,512) = W1/W2 fragment-tiling; [512,1024) = x -> bf16 streaming ----------------
__global__ __launch_bounds__(256) void k_conv(
    const float* __restrict__ x,
    const float* __restrict__ W1, const float* __restrict__ W2,
    unsigned short* __restrict__ W1f, unsigned short* __restrict__ W2f,
    unsigned short* __restrict__ xb16)
{
    int tid = threadIdx.x;
    if (blockIdx.x < 512){
        int b = blockIdx.x;
        int w = b >> 8;
        int e = (b >> 3) & 31;
        int kq = b & 7;
        const float* src = (w ? W2 : W1) + ((size_t)e << 18);
        unsigned short* dst = (w ? W2f : W1f) + ((size_t)e << 18);
        int n4 = (tid & 127) * 4;
        int kh = tid >> 7;
        #pragma unroll 1
        for (int kg = 0; kg < 4; kg++){
            int k0 = kq*64 + (kg*2 + kh)*8;
            float4 rows[8];
            #pragma unroll
            for (int j = 0; j < 8; j++)
                rows[j] = *(const float4*)&src[(size_t)(k0 + j)*512 + n4];
            unsigned short v0[8], v1[8], v2[8], v3[8];
            #pragma unroll
            for (int j = 0; j < 8; j++){
                v0[j] = f2bf(rows[j].x); v1[j] = f2bf(rows[j].y);
                v2[j] = f2bf(rows[j].z); v3[j] = f2bf(rows[j].w);
            }
            int kc = k0 >> 5, lb = ((k0 >> 3) & 3)*16;
            #pragma unroll
            for (int m = 0; m < 4; m++){
                int n = n4 + m;
                int nt = n >> 4, ln = lb + (n & 15);
                const unsigned short* vv = (m==0)?v0:(m==1)?v1:(m==2)?v2:v3;
                *(bf16x8*)(dst + (((size_t)(nt*16 + kc)*64 + ln) << 3)) = *(const bf16x8*)vv;
            }
        }
    } else {
        // x -> bf16, fully streaming (each block converts 65536 consecutive floats)
        int b = blockIdx.x - 512;
        size_t base = (size_t)b * 65536;
        const float* xs = x + base;
        unsigned short* xd = xb16 + base;
        #pragma unroll 1
        for (int i = 0; i < 32; i++){
            int o = (i*256 + tid)*8;
            float4 a = *(const float4*)(xs + o);
            float4 c = *(const float4*)(xs + o + 4);
            bf16x8 pk;
            pk[0]=(short)f2bf(a.x); pk[1]=(short)f2bf(a.y); pk[2]=(short)f2bf(a.z); pk[3]=(short)f2bf(a.w);
            pk[4]=(short)f2bf(c.x); pk[5]=(short)f2bf(c.y); pk[6]=(short)f2bf(c.z); pk[7]=(short)f2bf(c.w);
            *(bf16x8*)(xd + o) = pk;
        }
    }
}

// ---------------- gate: register-direct split-bf16 MFMA (64 tok/block) ----------------
__global__ __launch_bounds__(256) void k_gate(
    const float* __restrict__ x, const float* __restrict__ Wg,
    const unsigned short* __restrict__ WgHf, const unsigned short* __restrict__ WgLf,
    int* __restrict__ counts, int* __restrict__ gsl, float* __restrict__ wts,
    unsigned char* __restrict__ flags)
{
    __shared__ float lg2[64 * 33];
    __shared__ int lcnt[NE], lbase[NE];

    int tid = threadIdx.x;
    int t0 = blockIdx.x * 64;
    {
        int lane = tid & 63;
        int wv   = tid >> 6;
        int lg   = lane >> 4, ll = lane & 15;
        int tokl = wv*16 + ll;
        const float* xr = x + (size_t)(t0 + tokl)*DD;

        f32x4 acc0 = (f32x4)0.f, acc1 = (f32x4)0.f;
        #pragma unroll 4
        for (int kc = 0; kc < 16; kc++){
            int d0 = kc*32 + lg*8;
            float4 a = *(const float4*)(xr + d0);
            float4 b = *(const float4*)(xr + d0 + 4);
            unsigned short h[8], l[8];
            h[0]=f2bf(a.x); h[1]=f2bf(a.y); h[2]=f2bf(a.z); h[3]=f2bf(a.w);
            h[4]=f2bf(b.x); h[5]=f2bf(b.y); h[6]=f2bf(b.z); h[7]=f2bf(b.w);
            l[0]=f2bf(a.x-bf2f(h[0])); l[1]=f2bf(a.y-bf2f(h[1]));
            l[2]=f2bf(a.z-bf2f(h[2])); l[3]=f2bf(a.w-bf2f(h[3]));
            l[4]=f2bf(b.x-bf2f(h[4])); l[5]=f2bf(b.y-bf2f(h[5]));
            l[6]=f2bf(b.z-bf2f(h[6])); l[7]=f2bf(b.w-bf2f(h[7]));
            bf16x8 bh = *(bf16x8*)h, bl = *(bf16x8*)l;
            bf16x8 ah0 = *(const bf16x8*)(WgHf + ((size_t)(kc*64 + lane) << 3));
            bf16x8 al0 = *(const bf16x8*)(WgLf + ((size_t)(kc*64 + lane) << 3));
            bf16x8 ah1 = *(const bf16x8*)(WgHf + ((size_t)(1024 + kc*64 + lane) << 3));
            bf16x8 al1 = *(const bf16x8*)(WgLf + ((size_t)(1024 + kc*64 + lane) << 3));
            acc0 = __builtin_amdgcn_mfma_f32_16x16x32_bf16(ah0, bh, acc0, 0, 0, 0);
            acc0 = __builtin_amdgcn_mfma_f32_16x16x32_bf16(ah0, bl, acc0, 0, 0, 0);
            acc0 = __builtin_amdgcn_mfma_f32_16x16x32_bf16(al0, bh, acc0, 0, 0, 0);
            acc1 = __builtin_amdgcn_mfma_f32_16x16x32_bf16(ah1, bh, acc1, 0, 0, 0);
            acc1 = __builtin_amdgcn_mfma_f32_16x16x32_bf16(ah1, bl, acc1, 0, 0, 0);
            acc1 = __builtin_amdgcn_mfma_f32_16x16x32_bf16(al1, bh, acc1, 0, 0, 0);
        }
        #pragma unroll
        for (int i = 0; i < 4; i++){
            lg2[tokl*33 +      lg*4 + i] = acc0[i];
            lg2[tokl*33 + 16 + lg*4 + i] = acc1[i];
        }
    }
    if (tid < NE) lcnt[tid] = 0;
    __syncthreads();

    float w1 = 0.f, w2 = 0.f;
    int i1 = 0, i2 = 0, s1 = 0, s2 = 0;
    bool act = (tid < 64);
    if (act){
        int tok = t0 + tid;
        float acc[NE];
        #pragma unroll
        for (int n = 0; n < NE; n++) acc[n] = lg2[tid*33 + n];

        float v1 = -1e30f; i1 = -1;
        #pragma unroll
        for (int n = 0; n < NE; n++) if (acc[n] > v1){ v1 = acc[n]; i1 = n; }
        float v2 = -1e30f; i2 = -1;
        #pragma unroll
        for (int n = 0; n < NE; n++) if (n != i1 && acc[n] > v2){ v2 = acc[n]; i2 = n; }
        float v3 = -1e30f;
        #pragma unroll
        for (int n = 0; n < NE; n++) if (n != i1 && n != i2 && acc[n] > v3) v3 = acc[n];

        if (v2 - v3 >= 1e-4f){
            double ex  = exp((double)v2 - (double)v1);
            double inv = 1.0 / (1.0 + ex);
            w1 = (float)inv; w2 = (float)(ex * inv);
        } else {
            const float* xr = x + (size_t)tok * DD;
            float thresh = v2 - 1e-3f;
            unsigned cmask = 0u;
            #pragma unroll
            for (int n = 0; n < NE; n++) cmask |= (acc[n] >= thresh) ? (1u << n) : 0u;
            double dv1 = -1.0e300, dv2 = -1.0e300; int di1 = -1, di2 = -1;
            #pragma unroll 1
            for (int n = 0; n < NE; n++){
                if (!((cmask >> n) & 1u)) continue;
                double q0 = 0.0, q1 = 0.0, q2 = 0.0, q3 = 0.0;
                #pragma unroll 4
                for (int d = 0; d < DD; d += 4){
                    q0 = fma((double)xr[d+0], (double)Wg[(size_t)(d+0)*NE + n], q0);
                    q1 = fma((double)xr[d+1], (double)Wg[(size_t)(d+1)*NE + n], q1);
                    q2 = fma((double)xr[d+2], (double)Wg[(size_t)(d+2)*NE + n], q2);
                    q3 = fma((double)xr[d+3], (double)Wg[(size_t)(d+3)*NE + n], q3);
                }
                double sv = (q0 + q1) + (q2 + q3);
                if (sv > dv1){ dv2 = dv1; di2 = di1; dv1 = sv; di1 = n; }
                else if (sv > dv2){ dv2 = sv; di2 = n; }
            }
            i1 = di1; i2 = di2;
            double ex  = exp(dv2 - dv1);
            double inv = 1.0 / (1.0 + ex);
            w1 = (float)inv; w2 = (float)(ex * inv);
        }
        s1 = atomicAdd(&lcnt[i1], 1);
        s2 = atomicAdd(&lcnt[i2], 1);
    }
    __syncthreads();
    if (tid < NE && lcnt[tid] > 0) lbase[tid] = atomicAdd(&counts[tid], lcnt[tid]);
    __syncthreads();
    if (act){
        int tok = t0 + tid;
        int g1 = lbase[i1] + s1;
        int g2 = lbase[i2] + s2;
        bool k1 = g1 < CAP, k2 = g2 < CAP;
        if (k1){ gsl[i1*CAP + g1] = tok;               wts[i1*CAP + g1] = w1; }
        if (k2){ gsl[i2*CAP + g2] = tok | (1 << 20);   wts[i2*CAP + g2] = w2; }
        flags[tok] = (unsigned char)((k1 ? 1 : 0) | (k2 ? 2 : 0));
    }
}

// ---------------- fused expert FFN: depth-4 W prefetch ----------------
#define LW(A,B,C,D,P,CC) { \
    A = *(const bf16x8*)((P) + (CC)*512 + lane*8); \
    B = *(const bf16x8*)((P) + 8192 + (CC)*512 + lane*8); \
    C = *(const bf16x8*)((P) + 16384 + (CC)*512 + lane*8); \
    D = *(const bf16x8*)((P) + 24576 + (CC)*512 + lane*8); }

#define CHUNK1(CC,A,B,C,D) { \
    int base_ = (64*(CC) + 16*lg) ^ sw_; \
    bf16x8 x0_ = *(const bf16x8*)((char*)AH + (ll)*1024      + base_); \
    bf16x8 x1_ = *(const bf16x8*)((char*)AH + (16+ll)*1024   + base_); \
    bf16x8 x2_ = *(const bf16x8*)((char*)AH + (32+ll)*1024   + base_); \
    bf16x8 x3_ = *(const bf16x8*)((char*)AH + (48+ll)*1024   + base_); \
    __builtin_amdgcn_s_setprio(1); \
    acc[0][0]=__builtin_amdgcn_mfma_f32_16x16x32_bf16(A,x0_,acc[0][0],0,0,0); \
    acc[0][1]=__builtin_amdgcn_mfma_f32_16x16x32_bf16(A,x1_,acc[0][1],0,0,0); \
    acc[0][2]=__builtin_amdgcn_mfma_f32_16x16x32_bf16(A,x2_,acc[0][2],0,0,0); \
    acc[0][3]=__builtin_amdgcn_mfma_f32_16x16x32_bf16(A,x3_,acc[0][3],0,0,0); \
    acc[1][0]=__builtin_amdgcn_mfma_f32_16x16x32_bf16(B,x0_,acc[1][0],0,0,0); \
    acc[1][1]=__builtin_amdgcn_mfma_f32_16x16x32_bf16(B,x1_,acc[1][1],0,0,0); \
    acc[1][2]=__builtin_amdgcn_mfma_f32_16x16x32_bf16(B,x2_,acc[1][2],0,0,0); \
    acc[1][3]=__builtin_amdgcn_mfma_f32_16x16x32_bf16(B,x3_,acc[1][3],0,0,0); \
    acc[2][0]=__builtin_amdgcn_mfma_f32_16x16x32_bf16(C,x0_,acc[2][0],0,0,0); \
    acc[2][1]=__builtin_amdgcn_mfma_f32_16x16x32_bf16(C,x1_,acc[2][1],0,0,0); \
    acc[2][2]=__builtin_amdgcn_mfma_f32_16x16x32_bf16(C,x2_,acc[2][2],0,0,0); \
    acc[2][3]=__builtin_amdgcn_mfma_f32_16x16x32_bf16(C,x3_,acc[2][3],0,0,0); \
    acc[3][0]=__builtin_amdgcn_mfma_f32_16x16x32_bf16(D,x0_,acc[3][0],0,0,0); \
    acc[3][1]=__builtin_amdgcn_mfma_f32_16x16x32_bf16(D,x1_,acc[3][1],0,0,0); \
    acc[3][2]=__builtin_amdgcn_mfma_f32_16x16x32_bf16(D,x2_,acc[3][2],0,0,0); \
    acc[3][3]=__builtin_amdgcn_mfma_f32_16x16x32_bf16(D,x3_,acc[3][3],0,0,0); \
    __builtin_amdgcn_s_setprio(0); }

#define CHUNK2(CC,A,B,C,D) { \
    int base_ = (64*(CC) + 16*lg) ^ sw_; \
    bf16x8 x0_ = *(const bf16x8*)((char*)AH + (ll)*1024      + base_); \
    bf16x8 x1_ = *(const bf16x8*)((char*)AH + (16+ll)*1024   + base_); \
    bf16x8 x2_ = *(const bf16x8*)((char*)AH + (32+ll)*1024   + base_); \
    bf16x8 x3_ = *(const bf16x8*)((char*)AH + (48+ll)*1024   + base_); \
    __builtin_amdgcn_s_setprio(1); \
    acc[0][0]=__builtin_amdgcn_mfma_f32_16x16x32_bf16(x0_,A,acc[0][0],0,0,0); \
    acc[0][1]=__builtin_amdgcn_mfma_f32_16x16x32_bf16(x1_,A,acc[0][1],0,0,0); \
    acc[0][2]=__builtin_amdgcn_mfma_f32_16x16x32_bf16(x2_,A,acc[0][2],0,0,0); \
    acc[0][3]=__builtin_amdgcn_mfma_f32_16x16x32_bf16(x3_,A,acc[0][3],0,0,0); \
    acc[1][0]=__builtin_amdgcn_mfma_f32_16x16x32_bf16(x0_,B,acc[1][0],0,0,0); \
    acc[1][1]=__builtin_amdgcn_mfma_f32_16x16x32_bf16(x1_,B,acc[1][1],0,0,0); \
    acc[1][2]=__builtin_amdgcn_mfma_f32_16x16x32_bf16(x2_,B,acc[1][2],0,0,0); \
    acc[1][3]=__builtin_amdgcn_mfma_f32_16x16x32_bf16(x3_,B,acc[1][3],0,0,0); \
    acc[2][0]=__builtin_amdgcn_mfma_f32_16x16x32_bf16(x0_,C,acc[2][0],0,0,0); \
    acc[2][1]=__builtin_amdgcn_mfma_f32_16x16x32_bf16(x1_,C,acc[2][1],0,0,0); \
    acc[2][2]=__builtin_amdgcn_mfma_f32_16x16x32_bf16(x2_,C,acc[2][2],0,0,0); \
    acc[2][3]=__builtin_amdgcn_mfma_f32_16x16x32_bf16(x3_,C,acc[2][3],0,0,0); \
    acc[3][0]=__builtin_amdgcn_mfma_f32_16x16x32_bf16(x0_,D,acc[3][0],0,0,0); \
    acc[3][1]=__builtin_amdgcn_mfma_f32_16x16x32_bf16(x1_,D,acc[3][1],0,0,0); \
    acc[3][2]=__builtin_amdgcn_mfma_f32_16x16x32_bf16(x2_,D,acc[3][2],0,0,0); \
    acc[3][3]=__builtin_amdgcn_mfma_f32_16x16x32_bf16(x3_,D,acc[3][3],0,0,0); \
    __builtin_amdgcn_s_setprio(0); }

__global__ __launch_bounds__(512, 3) void k_ffn(
    const unsigned short* __restrict__ xb16,
    const unsigned short* __restrict__ W1f,
    const unsigned short* __restrict__ W2f,
    const float* __restrict__ b1, const float* __restrict__ b2,
    const int* __restrict__ counts,
    const int* __restrict__ gsl, const float* __restrict__ wts,
    float* __restrict__ y, unsigned short* __restrict__ y2h)
{
    __shared__ unsigned char AH[64 * 1024];

    int p  = blockIdx.x;
    int s  = p >> 3;
    int e  = ((s / NRB) << 3) | (p & 7);
    int rb = s % NRB;

    int cnt = counts[e]; if (cnt > CAP) cnt = CAP;
    int r0 = rb * BM;
    if (r0 >= cnt) return;

    int tid  = threadIdx.x;
    int lane = tid & 63;
    int wv   = tid >> 6;
    int lg   = lane >> 4;
    int ll   = lane & 15;
    int sw_  = (ll & 7) << 4;

    // ---- stage X from bf16 copy ----
    {
        int row = tid >> 3, seg = tid & 7;
        int gr  = r0 + row;
        char* rowb = (char*)AH + row * 1024;
        int rsw = (row & 7) << 4;
        if (gr < cnt){
            int tk = gsl[e*CAP + gr] & 0xFFFFF;
            const uint4* src = (const uint4*)(xb16 + (size_t)tk*DD + seg*64);
            #pragma unroll
            for (int j = 0; j < 8; j++){
                uint4 v = src[j];
                int chunk = seg*8 + j;
                *(uint4*)(rowb + ((chunk << 4) ^ rsw)) = v;
            }
        } else {
            uint4 zz; zz.x = zz.y = zz.z = zz.w = 0u;
            #pragma unroll
            for (int j = 0; j < 8; j++){
                int chunk = seg*8 + j;
                *(uint4*)(rowb + ((chunk << 4) ^ rsw)) = zz;
            }
        }
    }
    __syncthreads();

    f32x4 acc[4][4];
    #pragma unroll
    for (int a2 = 0; a2 < 4; a2++)
        #pragma unroll
        for (int tt = 0; tt < 4; tt++)
            acc[a2][tt] = (f32x4)0.f;

    // ---- layer 1 (swapped operands), depth-4 W prefetch ----
    {
        const unsigned short* Wa = W1f + ((size_t)e << 18) + (size_t)wv*32768;
        bf16x8 q0a,q0b,q0c,q0d, q1a,q1b,q1c,q1d, q2a,q2b,q2c,q2d, q3a,q3b,q3c,q3d;
        LW(q0a,q0b,q0c,q0d,Wa,0)
        LW(q1a,q1b,q1c,q1d,Wa,1)
        LW(q2a,q2b,q2c,q2d,Wa,2)
        LW(q3a,q3b,q3c,q3d,Wa,3)
        #pragma unroll 1
        for (int c = 0; c < 16; c += 4){
            CHUNK1(c,   q0a,q0b,q0c,q0d)
            if (c+4 < 16) LW(q0a,q0b,q0c,q0d,Wa,c+4)
            CHUNK1(c+1, q1a,q1b,q1c,q1d)
            if (c+5 < 16) LW(q1a,q1b,q1c,q1d,Wa,c+5)
            CHUNK1(c+2, q2a,q2b,q2c,q2d)
            if (c+6 < 16) LW(q2a,q2b,q2c,q2d,Wa,c+6)
            CHUNK1(c+3, q3a,q3b,q3c,q3d)
            if (c+7 < 16) LW(q3a,q3b,q3c,q3d,Wa,c+7)
        }
    }
    __syncthreads();

    // ---- h = relu(acc + b1) -> AH as h[tok][n], packed 8B writes ----
    #pragma unroll
    for (int a2 = 0; a2 < 4; a2++){
        int n0 = wv*64 + a2*16 + lg*4;
        float4 bv = *(const float4*)(b1 + e*HH + n0);
        #pragma unroll
        for (int tt = 0; tt < 4; tt++){
            int tok = tt*16 + ll;
            float h0 = acc[a2][tt][0] + bv.x; h0 = h0 > 0.f ? h0 : 0.f;
            float h1 = acc[a2][tt][1] + bv.y; h1 = h1 > 0.f ? h1 : 0.f;
            float h2 = acc[a2][tt][2] + bv.z; h2 = h2 > 0.f ? h2 : 0.f;
            float h3 = acc[a2][tt][3] + bv.w; h3 = h3 > 0.f ? h3 : 0.f;
            uint2 pk;
            pk.x = (unsigned)f2bf(h0) | ((unsigned)f2bf(h1) << 16);
            pk.y = (unsigned)f2bf(h2) | ((unsigned)f2bf(h3) << 16);
            int bofs = (n0*2) ^ ((tok & 7) << 4);
            *(uint2*)((char*)AH + tok*1024 + bofs) = pk;
            acc[a2][tt] = (f32x4)0.f;
        }
    }
    __syncthreads();

    // ---- layer 2, depth-4 W prefetch ----
    {
        const unsigned short* Wb = W2f + ((size_t)e << 18) + (size_t)wv*32768;
        bf16x8 q0a,q0b,q0c,q0d, q1a,q1b,q1c,q1d, q2a,q2b,q2c,q2d, q3a,q3b,q3c,q3d;
        LW(q0a,q0b,q0c,q0d,Wb,0)
        LW(q1a,q1b,q1c,q1d,Wb,1)
        LW(q2a,q2b,q2c,q2d,Wb,2)
        LW(q3a,q3b,q3c,q3d,Wb,3)
        #pragma unroll 1
        for (int kc = 0; kc < 16; kc += 4){
            CHUNK2(kc,   q0a,q0b,q0c,q0d)
            if (kc+4 < 16) LW(q0a,q0b,q0c,q0d,Wb,kc+4)
            CHUNK2(kc+1, q1a,q1b,q1c,q1d)
            if (kc+5 < 16) LW(q1a,q1b,q1c,q1d,Wb,kc+5)
            CHUNK2(kc+2, q2a,q2b,q2c,q2d)
            if (kc+6 < 16) LW(q2a,q2b,q2c,q2d,Wb,kc+6)
            CHUNK2(kc+3, q3a,q3b,q3c,q3d)
            if (kc+7 < 16) LW(q3a,q3b,q3c,q3d,Wb,kc+7)
        }
    }

    // ---- epilogue: top-1 -> y (fp32 plain), top-2 -> y2h (bf16, weighted) ----
    float bb[4];
    #pragma unroll
    for (int b_ = 0; b_ < 4; b_++)
        bb[b_] = b2[e*DD + wv*64 + b_*16 + ll];

    #pragma unroll
    for (int tt = 0; tt < 4; tt++){
        #pragma unroll
        for (int i = 0; i < 4; i++){
            int rl = tt*16 + lg*4 + i;
            int gr = r0 + rl;
            if (gr < cnt){
                int   v  = gsl[e*CAP + gr];
                int   tk = v & 0xFFFFF;
                float w  = wts[e*CAP + gr];
                if (v >> 20){
                    unsigned short* dst = y2h + (size_t)tk * DD;
                    #pragma unroll
                    for (int b_ = 0; b_ < 4; b_++){
                        int col = wv*64 + b_*16 + ll;
                        dst[col] = f2bf(w * (acc[b_][tt][i] + bb[b_]));
                    }
                } else {
                    float* dst = y + (size_t)tk * DD;
                    #pragma unroll
                    for (int b_ = 0; b_ < 4; b_++){
                        int col = wv*64 + b_*16 + ll;
                        dst[col] = w * (acc[b_][tt][i] + bb[b_]);
                    }
                }
            }
        }
    }
}

// ---------------- combine: y = [k1]y + [k2]bf16(y2), or passthrough x ----------------
__global__ __launch_bounds__(256) void k_comb(
    const float* __restrict__ x, const unsigned short* __restrict__ y2h,
    const unsigned char* __restrict__ flags, float* __restrict__ y)
{
    const float4* x4  = (const float4*)x;
    const uint2*  y24 = (const uint2*)y2h;
    float4* y4 = (float4*)y;
    int nthreads = gridDim.x * 256;
    int g = blockIdx.x * 256 + threadIdx.x;
    #pragma unroll 1
    for (long long idx = g; idx < (long long)BT * 128; idx += nthreads){
        int t = (int)(idx >> 7);
        int f = flags[t];
        if (f == 3){
            float4 a = y4[idx];
            uint2 p = y24[idx];
            a.x += bf2f((unsigned short)(p.x & 0xFFFF));
            a.y += bf2f((unsigned short)(p.x >> 16));
            a.z += bf2f((unsigned short)(p.y & 0xFFFF));
            a.w += bf2f((unsigned short)(p.y >> 16));
            y4[idx] = a;
        } else if (f == 2){
            uint2 p = y24[idx];
            float4 a;
            a.x = bf2f((unsigned short)(p.x & 0xFFFF));
            a.y = bf2f((unsigned short)(p.x >> 16));
            a.z = bf2f((unsigned short)(p.y & 0xFFFF));
            a.w = bf2f((unsigned short)(p.y >> 16));
            y4[idx] = a;
        } else if (f == 0){
            y4[idx] = x4[idx];
        } // f == 1: y already correct
    }
}

extern "C" void kernel_launch(void* const* d_in, const int* in_sizes, int n_in,
                              void* d_out, int out_size, void* d_ws, size_t ws_size,
                              hipStream_t stream)
{
    const float* x  = (const float*)d_in[0];
    const float* Wg = (const float*)d_in[1];
    const float* W1 = (const float*)d_in[2];
    const float* b1 = (const float*)d_in[3];
    const float* W2 = (const float*)d_in[4];
    const float* b2 = (const float*)d_in[5];
    float* y = (float*)d_out;

    char* ws = (char*)d_ws;
    unsigned short* W1f = (unsigned short*)(ws);
    unsigned short* W2f = (unsigned short*)(ws + 16777216);
    size_t b3 = 33554432;
    int*   counts = (int*)  (ws + b3);
    int*   gsl    = (int*)  (ws + b3 + 256);
    float* wts    = (float*)(ws + b3 + 256 + 655360);
    unsigned char* flags = (unsigned char*)(ws + b3 + 256 + 2*655360);
    unsigned short* WgHf = (unsigned short*)(ws + b3 + 256 + 2*655360 + 65536);
    unsigned short* WgLf = (unsigned short*)(ws + b3 + 256 + 2*655360 + 65536 + 32768);
    unsigned short* xb16 = (unsigned short*)(ws + 35651584);                // 67.1 MB
    unsigned short* y2h  = (unsigned short*)(ws + 35651584 + 67108864);     // 67.1 MB

    hipMemsetAsync(counts, 0, 256, stream);
    hipLaunchKernelGGL(k_wgprep, dim3(8), dim3(256), 0, stream, Wg, WgHf, WgLf);
    hipLaunchKernelGGL(k_conv, dim3(1024), dim3(256), 0, stream, x, W1, W2, W1f, W2f, xb16);
    hipLaunchKernelGGL(k_gate, dim3(BT/64), dim3(256), 0, stream, x, Wg, WgHf, WgLf, counts, gsl, wts, flags);
    hipLaunchKernelGGL(k_ffn,  dim3(NE*NRB), dim3(512), 0, stream, xb16, W1f, W2f, b1, b2, counts, gsl, wts, y, y2h);
    hipLaunchKernelGGL(k_comb, dim3(2048), dim3(256), 0, stream, x, y2h, flags, y);
}

// Round 17
// 343.618 us; speedup vs baseline: 1.2935x; 1.2935x over previous
//
#include <hip/hip_runtime.h>
#include <hip/hip_bf16.h>

#define BT 65536
#define DD 512
#define HH 512
#define NE 32
#define CAP 5120
#define BM 64
#define NRB 80   /* CAP/BM */

typedef float  f32x4  __attribute__((ext_vector_type(4)));
typedef short  bf16x8 __attribute__((ext_vector_type(8)));

__device__ __forceinline__ unsigned short f2bf(float f){
    unsigned int u = __builtin_bit_cast(unsigned int, f);
    unsigned int r = (u + 0x7fffu + ((u >> 16) & 1u)) >> 16;
    return (unsigned short)r;
}
__device__ __forceinline__ float bf2f(unsigned short h){
    unsigned int u = ((unsigned int)h) << 16;
    return __builtin_bit_cast(float, u);
}

// ---------------- Wg -> hi/lo MFMA A-fragments ----------------
__global__ __launch_bounds__(256) void k_wgprep(
    const float* __restrict__ Wg,
    unsigned short* __restrict__ WgHf, unsigned short* __restrict__ WgLf)
{
    int entry = blockIdx.x * 256 + threadIdx.x;   // 8 blocks x 256 = 2048 entries
    int ln = entry & 63;
    unsigned short h[8], l[8];
    #pragma unroll
    for (int j = 0; j < 8; j++){
        int d = ((entry >> 6) & 15)*32 + (ln >> 4)*8 + j;
        int e = (entry >> 10)*16 + (ln & 15);
        float v = Wg[d*NE + e];
        unsigned short hi = f2bf(v);
        h[j] = hi;
        l[j] = f2bf(v - bf2f(hi));
    }
    *(bf16x8*)(WgHf + (size_t)entry*8) = *(bf16x8*)h;
    *(bf16x8*)(WgLf + (size_t)entry*8) = *(bf16x8*)l;
}

// ---------------- prep: blocks [0,1024) = register-direct MFMA gate (64 tok); [1024,1536) = weight conv ----------------
__global__ __launch_bounds__(256) void k_prep(
    const float* __restrict__ x, const float* __restrict__ Wg,
    const float* __restrict__ W1, const float* __restrict__ W2,
    const unsigned short* __restrict__ WgHf, const unsigned short* __restrict__ WgLf,
    unsigned short* __restrict__ W1f, unsigned short* __restrict__ W2f,
    int* __restrict__ counts, int* __restrict__ gsl, float* __restrict__ wts,
    unsigned char* __restrict__ flags, unsigned short* __restrict__ xb16)
{
    __shared__ float lg2[64 * 33];            // logits [tok][expert], padded
    __shared__ int lcnt[NE], lbase[NE];

    int tid = threadIdx.x;

    if (blockIdx.x >= 1024){
        // ---------------- weight convert (float4-vectorized, coalesced rows) ----------------
        int b = blockIdx.x - 1024;             // 0..511
        int w = b >> 8;
        int e = (b >> 3) & 31;
        int kq = b & 7;
        const float* src = (w ? W2 : W1) + ((size_t)e << 18);
        unsigned short* dst = (w ? W2f : W1f) + ((size_t)e << 18);
        int n4 = (tid & 127) * 4;
        int kh = tid >> 7;
        #pragma unroll 1
        for (int kg = 0; kg < 4; kg++){
            int k0 = kq*64 + (kg*2 + kh)*8;
            float4 rows[8];
            #pragma unroll
            for (int j = 0; j < 8; j++)
                rows[j] = *(const float4*)&src[(size_t)(k0 + j)*512 + n4];
            unsigned short v0[8], v1[8], v2[8], v3[8];
            #pragma unroll
            for (int j = 0; j < 8; j++){
                v0[j] = f2bf(rows[j].x); v1[j] = f2bf(rows[j].y);
                v2[j] = f2bf(rows[j].z); v3[j] = f2bf(rows[j].w);
            }
            int kc = k0 >> 5, lb = ((k0 >> 3) & 3)*16;
            #pragma unroll
            for (int m = 0; m < 4; m++){
                int n = n4 + m;
                int nt = n >> 4, ln = lb + (n & 15);
                const unsigned short* vv = (m==0)?v0:(m==1)?v1:(m==2)?v2:v3;
                *(bf16x8*)(dst + (((size_t)(nt*16 + kc)*64 + ln) << 3)) = *(const bf16x8*)vv;
            }
        }
        return;
    }

    // ---------------- gate: register-direct split-bf16 MFMA, xb16 byproduct ----------------
    int t0 = blockIdx.x * 64;
    {
        int lane = tid & 63;
        int wv   = tid >> 6;
        int lg   = lane >> 4, ll = lane & 15;
        int tokl = wv*16 + ll;
        const float* xr = x + (size_t)(t0 + tokl)*DD;

        f32x4 acc0 = (f32x4)0.f, acc1 = (f32x4)0.f;
        #pragma unroll 4
        for (int kc = 0; kc < 16; kc++){
            int d0 = kc*32 + lg*8;
            float4 a = *(const float4*)(xr + d0);
            float4 b = *(const float4*)(xr + d0 + 4);
            unsigned short h[8], l[8];
            h[0]=f2bf(a.x); h[1]=f2bf(a.y); h[2]=f2bf(a.z); h[3]=f2bf(a.w);
            h[4]=f2bf(b.x); h[5]=f2bf(b.y); h[6]=f2bf(b.z); h[7]=f2bf(b.w);
            l[0]=f2bf(a.x-bf2f(h[0])); l[1]=f2bf(a.y-bf2f(h[1]));
            l[2]=f2bf(a.z-bf2f(h[2])); l[3]=f2bf(a.w-bf2f(h[3]));
            l[4]=f2bf(b.x-bf2f(h[4])); l[5]=f2bf(b.y-bf2f(h[5]));
            l[6]=f2bf(b.z-bf2f(h[6])); l[7]=f2bf(b.w-bf2f(h[7]));
            bf16x8 bh = *(bf16x8*)h, bl = *(bf16x8*)l;
            *(bf16x8*)(xb16 + (size_t)(t0 + tokl)*DD + d0) = bh;   // byproduct for ffn
            bf16x8 ah0 = *(const bf16x8*)(WgHf + ((size_t)(kc*64 + lane) << 3));
            bf16x8 al0 = *(const bf16x8*)(WgLf + ((size_t)(kc*64 + lane) << 3));
            bf16x8 ah1 = *(const bf16x8*)(WgHf + ((size_t)(1024 + kc*64 + lane) << 3));
            bf16x8 al1 = *(const bf16x8*)(WgLf + ((size_t)(1024 + kc*64 + lane) << 3));
            acc0 = __builtin_amdgcn_mfma_f32_16x16x32_bf16(ah0, bh, acc0, 0, 0, 0);
            acc0 = __builtin_amdgcn_mfma_f32_16x16x32_bf16(ah0, bl, acc0, 0, 0, 0);
            acc0 = __builtin_amdgcn_mfma_f32_16x16x32_bf16(al0, bh, acc0, 0, 0, 0);
            acc1 = __builtin_amdgcn_mfma_f32_16x16x32_bf16(ah1, bh, acc1, 0, 0, 0);
            acc1 = __builtin_amdgcn_mfma_f32_16x16x32_bf16(ah1, bl, acc1, 0, 0, 0);
            acc1 = __builtin_amdgcn_mfma_f32_16x16x32_bf16(al1, bh, acc1, 0, 0, 0);
        }
        #pragma unroll
        for (int i = 0; i < 4; i++){
            lg2[tokl*33 +      lg*4 + i] = acc0[i];
            lg2[tokl*33 + 16 + lg*4 + i] = acc1[i];
        }
    }
    if (tid < NE) lcnt[tid] = 0;
    __syncthreads();

    float w1 = 0.f, w2 = 0.f;
    int i1 = 0, i2 = 0, s1 = 0, s2 = 0;
    bool act = (tid < 64);
    if (act){
        int tok = t0 + tid;
        float acc[NE];
        #pragma unroll
        for (int n = 0; n < NE; n++) acc[n] = lg2[tid*33 + n];

        float v1 = -1e30f; i1 = -1;
        #pragma unroll
        for (int n = 0; n < NE; n++) if (acc[n] > v1){ v1 = acc[n]; i1 = n; }
        float v2 = -1e30f; i2 = -1;
        #pragma unroll
        for (int n = 0; n < NE; n++) if (n != i1 && acc[n] > v2){ v2 = acc[n]; i2 = n; }
        float v3 = -1e30f;
        #pragma unroll
        for (int n = 0; n < NE; n++) if (n != i1 && n != i2 && acc[n] > v3) v3 = acc[n];

        if (v2 - v3 >= 1e-4f){
            double ex  = exp((double)v2 - (double)v1);
            double inv = 1.0 / (1.0 + ex);
            w1 = (float)inv; w2 = (float)(ex * inv);
        } else {
            const float* xr = x + (size_t)tok * DD;
            float thresh = v2 - 1e-3f;
            unsigned cmask = 0u;
            #pragma unroll
            for (int n = 0; n < NE; n++) cmask |= (acc[n] >= thresh) ? (1u << n) : 0u;
            double dv1 = -1.0e300, dv2 = -1.0e300; int di1 = -1, di2 = -1;
            #pragma unroll 1
            for (int n = 0; n < NE; n++){
                if (!((cmask >> n) & 1u)) continue;
                double q0 = 0.0, q1 = 0.0, q2 = 0.0, q3 = 0.0;
                #pragma unroll 4
                for (int d = 0; d < DD; d += 4){
                    q0 = fma((double)xr[d+0], (double)Wg[(size_t)(d+0)*NE + n], q0);
                    q1 = fma((double)xr[d+1], (double)Wg[(size_t)(d+1)*NE + n], q1);
                    q2 = fma((double)xr[d+2], (double)Wg[(size_t)(d+2)*NE + n], q2);
                    q3 = fma((double)xr[d+3], (double)Wg[(size_t)(d+3)*NE + n], q3);
                }
                double sv = (q0 + q1) + (q2 + q3);
                if (sv > dv1){ dv2 = dv1; di2 = di1; dv1 = sv; di1 = n; }
                else if (sv > dv2){ dv2 = sv; di2 = n; }
            }
            i1 = di1; i2 = di2;
            double ex  = exp(dv2 - dv1);
            double inv = 1.0 / (1.0 + ex);
            w1 = (float)inv; w2 = (float)(ex * inv);
        }
        s1 = atomicAdd(&lcnt[i1], 1);
        s2 = atomicAdd(&lcnt[i2], 1);
    }
    __syncthreads();
    if (tid < NE && lcnt[tid] > 0) lbase[tid] = atomicAdd(&counts[tid], lcnt[tid]);
    __syncthreads();
    if (act){
        int tok = t0 + tid;
        int g1 = lbase[i1] + s1;
        int g2 = lbase[i2] + s2;
        bool k1 = g1 < CAP, k2 = g2 < CAP;
        if (k1){ gsl[i1*CAP + g1] = tok;               wts[i1*CAP + g1] = w1; }
        if (k2){ gsl[i2*CAP + g2] = tok | (1 << 20);   wts[i2*CAP + g2] = w2; }
        flags[tok] = (unsigned char)((k1 ? 1 : 0) | (k2 ? 2 : 0));
    }
}

// ---------------- fused expert FFN (R15 core; Y1BF16 selects epilogue destination) ----------------
template<int Y1BF16>
__global__ __launch_bounds__(512, 4) void k_ffn(
    const unsigned short* __restrict__ xb16,
    const unsigned short* __restrict__ W1f,
    const unsigned short* __restrict__ W2f,
    const float* __restrict__ b1, const float* __restrict__ b2,
    const int* __restrict__ counts,
    const int* __restrict__ gsl, const float* __restrict__ wts,
    float* __restrict__ y, unsigned short* __restrict__ y1h,
    unsigned short* __restrict__ y2h)
{
    __shared__ unsigned char AH[64 * 1024];   // [tok(64)][512 bf16], 16B-chunk XOR swizzle ((tok&7)<<4)

    int p  = blockIdx.x;
    int s  = p >> 3;
    int e  = ((s / NRB) << 3) | (p & 7);
    int rb = s % NRB;

    int cnt = counts[e]; if (cnt > CAP) cnt = CAP;
    int r0 = rb * BM;
    if (r0 >= cnt) return;

    int tid  = threadIdx.x;
    int lane = tid & 63;
    int wv   = tid >> 6;
    int lg   = lane >> 4;
    int ll   = lane & 15;

    // ---- stage X from bf16 copy ----
    {
        int row = tid >> 3, seg = tid & 7;
        int gr  = r0 + row;
        char* rowb = (char*)AH + row * 1024;
        int rsw = (row & 7) << 4;
        if (gr < cnt){
            int tk = gsl[e*CAP + gr] & 0xFFFFF;
            const uint4* src = (const uint4*)(xb16 + (size_t)tk*DD + seg*64);
            #pragma unroll
            for (int j = 0; j < 8; j++){
                uint4 v = src[j];
                int chunk = seg*8 + j;
                *(uint4*)(rowb + ((chunk << 4) ^ rsw)) = v;
            }
        } else {
            uint4 zz; zz.x = zz.y = zz.z = zz.w = 0u;
            #pragma unroll
            for (int j = 0; j < 8; j++){
                int chunk = seg*8 + j;
                *(uint4*)(rowb + ((chunk << 4) ^ rsw)) = zz;
            }
        }
    }
    __syncthreads();

    f32x4 acc[4][4];
    #pragma unroll
    for (int a2 = 0; a2 < 4; a2++)
        #pragma unroll
        for (int tt = 0; tt < 4; tt++)
            acc[a2][tt] = (f32x4)0.f;

    // ---- layer 1 (swapped): depth-1 f0/f1 W prefetch ----
    {
        const unsigned short* Wa = W1f + ((size_t)e << 18) + (size_t)wv*32768;
        bf16x8 f0[4], f1[4];
        #pragma unroll
        for (int a2 = 0; a2 < 4; a2++)
            f0[a2] = *(const bf16x8*)(Wa + a2*8192 + lane*8);
        #pragma unroll 1
        for (int c = 0; c < 16; c += 2){
            #pragma unroll
            for (int a2 = 0; a2 < 4; a2++)
                f1[a2] = *(const bf16x8*)(Wa + a2*8192 + (c+1)*512 + lane*8);
            {
                bf16x8 bx[4];
                #pragma unroll
                for (int tt = 0; tt < 4; tt++){
                    int tok = tt*16 + ll;
                    int bofs = (64*c + 16*lg) ^ ((tok & 7) << 4);
                    bx[tt] = *(const bf16x8*)((char*)AH + tok*1024 + bofs);
                }
                __builtin_amdgcn_s_setprio(1);
                #pragma unroll
                for (int a2 = 0; a2 < 4; a2++)
                    #pragma unroll
                    for (int tt = 0; tt < 4; tt++)
                        acc[a2][tt] = __builtin_amdgcn_mfma_f32_16x16x32_bf16(f0[a2], bx[tt], acc[a2][tt], 0, 0, 0);
                __builtin_amdgcn_s_setprio(0);
            }
            if (c + 2 < 16){
                #pragma unroll
                for (int a2 = 0; a2 < 4; a2++)
                    f0[a2] = *(const bf16x8*)(Wa + a2*8192 + (c+2)*512 + lane*8);
            }
            {
                bf16x8 bx[4];
                #pragma unroll
                for (int tt = 0; tt < 4; tt++){
                    int tok = tt*16 + ll;
                    int bofs = (64*(c+1) + 16*lg) ^ ((tok & 7) << 4);
                    bx[tt] = *(const bf16x8*)((char*)AH + tok*1024 + bofs);
                }
                __builtin_amdgcn_s_setprio(1);
                #pragma unroll
                for (int a2 = 0; a2 < 4; a2++)
                    #pragma unroll
                    for (int tt = 0; tt < 4; tt++)
                        acc[a2][tt] = __builtin_amdgcn_mfma_f32_16x16x32_bf16(f1[a2], bx[tt], acc[a2][tt], 0, 0, 0);
                __builtin_amdgcn_s_setprio(0);
            }
        }
    }
    __syncthreads();

    // ---- h = relu(acc + b1) -> AH as h[tok][n], packed 8B writes ----
    #pragma unroll
    for (int a2 = 0; a2 < 4; a2++){
        int n0 = wv*64 + a2*16 + lg*4;
        float4 bv = *(const float4*)(b1 + e*HH + n0);
        #pragma unroll
        for (int tt = 0; tt < 4; tt++){
            int tok = tt*16 + ll;
            float h0 = acc[a2][tt][0] + bv.x; h0 = h0 > 0.f ? h0 : 0.f;
            float h1 = acc[a2][tt][1] + bv.y; h1 = h1 > 0.f ? h1 : 0.f;
            float h2 = acc[a2][tt][2] + bv.z; h2 = h2 > 0.f ? h2 : 0.f;
            float h3 = acc[a2][tt][3] + bv.w; h3 = h3 > 0.f ? h3 : 0.f;
            uint2 pk;
            pk.x = (unsigned)f2bf(h0) | ((unsigned)f2bf(h1) << 16);
            pk.y = (unsigned)f2bf(h2) | ((unsigned)f2bf(h3) << 16);
            int bofs = (n0*2) ^ ((tok & 7) << 4);
            *(uint2*)((char*)AH + tok*1024 + bofs) = pk;
            acc[a2][tt] = (f32x4)0.f;
        }
    }
    __syncthreads();

    // ---- layer 2 ----
    {
        const unsigned short* Wb = W2f + ((size_t)e << 18) + (size_t)wv*32768;
        bf16x8 f0[4], f1[4];
        #pragma unroll
        for (int b_ = 0; b_ < 4; b_++)
            f0[b_] = *(const bf16x8*)(Wb + b_*8192 + lane*8);
        #pragma unroll 1
        for (int kc = 0; kc < 16; kc += 2){
            #pragma unroll
            for (int b_ = 0; b_ < 4; b_++)
                f1[b_] = *(const bf16x8*)(Wb + b_*8192 + (kc+1)*512 + lane*8);
            {
                bf16x8 ah[4];
                #pragma unroll
                for (int tt = 0; tt < 4; tt++){
                    int tok = tt*16 + ll;
                    int bofs = (64*kc + 16*lg) ^ ((tok & 7) << 4);
                    ah[tt] = *(const bf16x8*)((char*)AH + tok*1024 + bofs);
                }
                __builtin_amdgcn_s_setprio(1);
                #pragma unroll
                for (int b_ = 0; b_ < 4; b_++)
                    #pragma unroll
                    for (int tt = 0; tt < 4; tt++)
                        acc[b_][tt] = __builtin_amdgcn_mfma_f32_16x16x32_bf16(ah[tt], f0[b_], acc[b_][tt], 0, 0, 0);
                __builtin_amdgcn_s_setprio(0);
            }
            if (kc + 2 < 16){
                #pragma unroll
                for (int b_ = 0; b_ < 4; b_++)
                    f0[b_] = *(const bf16x8*)(Wb + b_*8192 + (kc+2)*512 + lane*8);
            }
            {
                bf16x8 ah[4];
                #pragma unroll
                for (int tt = 0; tt < 4; tt++){
                    int tok = tt*16 + ll;
                    int bofs = (64*(kc+1) + 16*lg) ^ ((tok & 7) << 4);
                    ah[tt] = *(const bf16x8*)((char*)AH + tok*1024 + bofs);
                }
                __builtin_amdgcn_s_setprio(1);
                #pragma unroll
                for (int b_ = 0; b_ < 4; b_++)
                    #pragma unroll
                    for (int tt = 0; tt < 4; tt++)
                        acc[b_][tt] = __builtin_amdgcn_mfma_f32_16x16x32_bf16(ah[tt], f1[b_], acc[b_][tt], 0, 0, 0);
                __builtin_amdgcn_s_setprio(0);
            }
        }
    }

    // ---- epilogue ----
    float bb[4];
    #pragma unroll
    for (int b_ = 0; b_ < 4; b_++)
        bb[b_] = b2[e*DD + wv*64 + b_*16 + ll];

    #pragma unroll
    for (int tt = 0; tt < 4; tt++){
        #pragma unroll
        for (int i = 0; i < 4; i++){
            int rl = tt*16 + lg*4 + i;
            int gr = r0 + rl;
            if (gr < cnt){
                int   v  = gsl[e*CAP + gr];
                int   tk = v & 0xFFFFF;
                float w  = wts[e*CAP + gr];
                if (Y1BF16){
                    unsigned short* dst = ((v >> 20) ? y2h : y1h) + (size_t)tk * DD;
                    #pragma unroll
                    for (int b_ = 0; b_ < 4; b_++){
                        int col = wv*64 + b_*16 + ll;
                        dst[col] = f2bf(w * (acc[b_][tt][i] + bb[b_]));
                    }
                } else {
                    if (v >> 20){
                        unsigned short* dst = y2h + (size_t)tk * DD;
                        #pragma unroll
                        for (int b_ = 0; b_ < 4; b_++){
                            int col = wv*64 + b_*16 + ll;
                            dst[col] = f2bf(w * (acc[b_][tt][i] + bb[b_]));
                        }
                    } else {
                        float* dst = y + (size_t)tk * DD;
                        #pragma unroll
                        for (int b_ = 0; b_ < 4; b_++){
                            int col = wv*64 + b_*16 + ll;
                            dst[col] = w * (acc[b_][tt][i] + bb[b_]);
                        }
                    }
                }
            }
        }
    }
}

// ---------------- combine ----------------
template<int Y1BF16>
__global__ __launch_bounds__(256) void k_comb(
    const float* __restrict__ x, const unsigned short* __restrict__ y1h,
    const unsigned short* __restrict__ y2h,
    const unsigned char* __restrict__ flags, float* __restrict__ y)
{
    const float4* x4  = (const float4*)x;
    const uint2*  y14 = (const uint2*)y1h;
    const uint2*  y24 = (const uint2*)y2h;
    float4* y4 = (float4*)y;
    int nthreads = gridDim.x * 256;
    int g = blockIdx.x * 256 + threadIdx.x;
    #pragma unroll 1
    for (long long idx = g; idx < (long long)BT * 128; idx += nthreads){
        int t = (int)(idx >> 7);
        int f = flags[t];
        if (Y1BF16){
            float4 a; a.x = a.y = a.z = a.w = 0.f;
            if (f == 0){
                a = x4[idx];
            } else {
                if (f & 1){
                    uint2 p = y14[idx];
                    a.x += bf2f((unsigned short)(p.x & 0xFFFF));
                    a.y += bf2f((unsigned short)(p.x >> 16));
                    a.z += bf2f((unsigned short)(p.y & 0xFFFF));
                    a.w += bf2f((unsigned short)(p.y >> 16));
                }
                if (f & 2){
                    uint2 p = y24[idx];
                    a.x += bf2f((unsigned short)(p.x & 0xFFFF));
                    a.y += bf2f((unsigned short)(p.x >> 16));
                    a.z += bf2f((unsigned short)(p.y & 0xFFFF));
                    a.w += bf2f((unsigned short)(p.y >> 16));
                }
            }
            y4[idx] = a;
        } else {
            if (f == 3){
                float4 a = y4[idx];
                uint2 p = y24[idx];
                a.x += bf2f((unsigned short)(p.x & 0xFFFF));
                a.y += bf2f((unsigned short)(p.x >> 16));
                a.z += bf2f((unsigned short)(p.y & 0xFFFF));
                a.w += bf2f((unsigned short)(p.y >> 16));
                y4[idx] = a;
            } else if (f == 2){
                uint2 p = y24[idx];
                float4 a;
                a.x = bf2f((unsigned short)(p.x & 0xFFFF));
                a.y = bf2f((unsigned short)(p.x >> 16));
                a.z = bf2f((unsigned short)(p.y & 0xFFFF));
                a.w = bf2f((unsigned short)(p.y >> 16));
                y4[idx] = a;
            } else if (f == 0){
                y4[idx] = x4[idx];
            }
        }
    }
}

extern "C" void kernel_launch(void* const* d_in, const int* in_sizes, int n_in,
                              void* d_out, int out_size, void* d_ws, size_t ws_size,
                              hipStream_t stream)
{
    const float* x  = (const float*)d_in[0];
    const float* Wg = (const float*)d_in[1];
    const float* W1 = (const float*)d_in[2];
    const float* b1 = (const float*)d_in[3];
    const float* W2 = (const float*)d_in[4];
    const float* b2 = (const float*)d_in[5];
    float* y = (float*)d_out;

    char* ws = (char*)d_ws;
    unsigned short* W1f = (unsigned short*)(ws);
    unsigned short* W2f = (unsigned short*)(ws + 16777216);
    size_t b3 = 33554432;
    int*   counts = (int*)  (ws + b3);
    int*   gsl    = (int*)  (ws + b3 + 256);
    float* wts    = (float*)(ws + b3 + 256 + 655360);
    unsigned char* flags = (unsigned char*)(ws + b3 + 256 + 2*655360);
    unsigned short* WgHf = (unsigned short*)(ws + b3 + 256 + 2*655360 + 65536);
    unsigned short* WgLf = (unsigned short*)(ws + b3 + 256 + 2*655360 + 65536 + 32768);
    unsigned short* xb16 = (unsigned short*)(ws + 35651584);                         // 67.1 MB
    unsigned short* y2h  = (unsigned short*)(ws + 35651584 + 67108864);              // 67.1 MB
    unsigned short* y1h  = (unsigned short*)(ws + 35651584 + 2ull*67108864);         // 67.1 MB (guarded)

    bool big = ws_size >= (35651584ull + 3ull*67108864ull);

    hipMemsetAsync(counts, 0, 256, stream);
    hipLaunchKernelGGL(k_wgprep, dim3(8), dim3(256), 0, stream, Wg, WgHf, WgLf);
    hipLaunchKernelGGL(k_prep, dim3(1024 + 512), dim3(256), 0, stream,
                       x, Wg, W1, W2, WgHf, WgLf, W1f, W2f, counts, gsl, wts, flags, xb16);
    if (big){
        hipLaunchKernelGGL((k_ffn<1>), dim3(NE*NRB), dim3(512), 0, stream,
                           xb16, W1f, W2f, b1, b2, counts, gsl, wts, y, y1h, y2h);
        hipLaunchKernelGGL((k_comb<1>), dim3(2048), dim3(256), 0, stream, x, y1h, y2h, flags, y);
    } else {
        hipLaunchKernelGGL((k_ffn<0>), dim3(NE*NRB), dim3(512), 0, stream,
                           xb16, W1f, W2f, b1, b2, counts, gsl, wts, y, y1h, y2h);
        hipLaunchKernelGGL((k_comb<0>), dim3(2048), dim3(256), 0, stream, x, y1h, y2h, flags, y);
    }
}